// Round 15
// baseline (209.216 us; speedup 1.0000x reference)
//
#include <hip/hip_runtime.h>
#include <math.h>

#define NN    100000
#define NE    3200000
#define FEAT  128
#define HID   16
#define NCLS  20
#define NBKT  391            // ceil(NN/256) coarse buckets (dst >> 8)
#define NBLKC 512            // blocks for bucket count/scatter
#define TB    1024           // threads/block for kA/kC/kD
#define CHNK  ((NE + NBLKC - 1) / NBLKC)   // 6250 edges per kC block
#define KC_SL 7              // ceil(CHNK/TB) register-cache slots
#define KD_SL 9              // 9*TB=9216 >= max coarse-bucket degree (~8.6K)
#define NSB   98             // ceil(NN/1024) blocks for node-sort kernels

typedef _Float16 hf;
typedef _Float16 hf2 __attribute__((ext_vector_type(2)));

__device__ __forceinline__ float dot2f(hf2 a, hf2 b) {
#if defined(__has_builtin) && __has_builtin(__builtin_amdgcn_fdot2)
  return __builtin_amdgcn_fdot2(a, b, 0.0f, false);
#else
  return fmaf((float)a.y, (float)b.y, (float)a.x * (float)b.x);
#endif
}

// ---- embedding gather + MLP -> fp16 features + invn ------------------------
__global__ __launch_bounds__(256) void k_embed_mlp(
    const int* __restrict__ ids, const float* __restrict__ emb,
    const float* __restrict__ W1, const float* __restrict__ b1,
    hf* __restrict__ hx, float* __restrict__ invn) {
  __shared__ float sW[FEAT * HID];        // 8 KB
  __shared__ float sx[16][FEAT + 4];      // 16 staged rows, 132f stride
  for (int i = threadIdx.x; i < FEAT * HID; i += 256) sW[i] = W1[i];
  int node = blockIdx.x * 16 + (threadIdx.x >> 4);
  int nl = threadIdx.x >> 4;              // local node 0..15
  int k = threadIdx.x & 15;
  const float4* er = (const float4*)(emb + (size_t)ids[node] * FEAT);
  float4 ra = er[2 * k], rb = er[2 * k + 1];     // coalesced 32B/lane
  *(float4*)&sx[nl][8 * k] = ra;
  *(float4*)&sx[nl][8 * k + 4] = rb;
  __syncthreads();
  float acc = b1[k];
  const float* xr = sx[nl];
#pragma unroll
  for (int j = 0; j < FEAT; ++j) acc = fmaf(xr[j], sW[j * HID + k], acc);
  acc = fmaxf(acc, 0.0f);
  hf h = (hf)acc;
  float a = (float)h;
  float n2 = a * a;
  n2 += __shfl_xor(n2, 1); n2 += __shfl_xor(n2, 2);
  n2 += __shfl_xor(n2, 4); n2 += __shfl_xor(n2, 8);
  hx[node * HID + k] = h;
  if (k == 0) invn[node] = rsqrtf(fmaxf(n2, 1e-24f));  // 1/max(||x||,1e-12)
}

// ---------------- CSR build: bucketed counting sort -------------------------
__global__ __launch_bounds__(256) void k_zero(int* __restrict__ c, int n) {
  int i = blockIdx.x * 256 + threadIdx.x;
  if (i < n) c[i] = 0;
}

__global__ __launch_bounds__(TB) void kA(
    const int* __restrict__ edst, int* __restrict__ gcount) {
  __shared__ int h[NBKT];
  for (int i = threadIdx.x; i < NBKT; i += TB) h[i] = 0;
  __syncthreads();
  int s0 = blockIdx.x * CHNK, s1 = min(NE, s0 + CHNK);
  for (int i = s0 + threadIdx.x; i < s1; i += TB)
    atomicAdd(&h[__builtin_nontemporal_load(edst + i) >> 8], 1);
  __syncthreads();
  for (int i = threadIdx.x; i < NBKT; i += TB)
    if (h[i]) atomicAdd(&gcount[i], h[i]);
}

__global__ __launch_bounds__(512) void kB(
    const int* __restrict__ gcount, int* __restrict__ gbase,
    int* __restrict__ gcur, int* __restrict__ rowptr) {
  __shared__ int sd[512];
  int tid = threadIdx.x;
  int v = (tid < NBKT) ? gcount[tid] : 0;
  sd[tid] = v;
  __syncthreads();
  for (int off = 1; off < 512; off <<= 1) {
    int t = (tid >= off) ? sd[tid - off] : 0;
    __syncthreads();
    sd[tid] += t;
    __syncthreads();
  }
  if (tid < NBKT) { int b = sd[tid] - v; gbase[tid] = b; gcur[tid] = b; }
  if (tid == 0) rowptr[NN] = NE;
}

// kC: block-local LDS counting sort, COALESCED run write-out.
__global__ __launch_bounds__(TB) void kC(
    const int* __restrict__ esrc, const int* __restrict__ edst,
    int* __restrict__ gcur, unsigned* __restrict__ strm) {
  __shared__ int h[NBKT];            // counts, then scatter cursors
  __shared__ int lofs[NBKT + 1];     // local exclusive offsets
  __shared__ int basel[NBKT];        // reserved global run bases
  __shared__ int sd[512];
  __shared__ unsigned lsort[CHNK];   // 25 KB locally sorted chunk
  int tid = threadIdx.x;
  for (int i = tid; i < NBKT; i += TB) h[i] = 0;
  __syncthreads();
  int s0 = blockIdx.x * CHNK, s1 = min(NE, s0 + CHNK);
  int total = s1 - s0;
  int dc[KC_SL], sc[KC_SL];
#pragma unroll
  for (int j = 0; j < KC_SL; ++j) {
    int i = s0 + tid + j * TB;
    if (i < s1) {
      int d = __builtin_nontemporal_load(edst + i);
      dc[j] = d;
      sc[j] = __builtin_nontemporal_load(esrc + i);
      atomicAdd(&h[d >> 8], 1);
    }
  }
  __syncthreads();                                   // hist complete
  int v = (tid < NBKT) ? h[tid] : 0;
  if (tid < 512) sd[tid] = v;
  __syncthreads();
  for (int off = 1; off < 512; off <<= 1) {
    int t = (tid < 512 && tid >= off) ? sd[tid - off] : 0;
    __syncthreads();
    if (tid < 512) sd[tid] += t;
    __syncthreads();
  }
  if (tid < NBKT) {
    lofs[tid] = sd[tid] - v;
    basel[tid] = v ? atomicAdd(&gcur[tid], v) : 0;
  }
  if (tid == 0) lofs[NBKT] = total;
  __syncthreads();                                   // scan consumed
  for (int i = tid; i < NBKT; i += TB) h[i] = 0;     // cursors
  __syncthreads();
#pragma unroll
  for (int j = 0; j < KC_SL; ++j) {
    int i = s0 + tid + j * TB;
    if (i < s1) {
      int d = dc[j];
      int b = d >> 8;
      int p = lofs[b] + atomicAdd(&h[b], 1);
      lsort[p] = (unsigned)sc[j] | ((unsigned)(d & 255) << 17);
    }
  }
  __syncthreads();                                   // lsort ready
  for (int j = tid; j < total; j += TB) {
    int lo = 0, hi = NBKT;                           // lofs[lo]<=j<lofs[hi]
    while (hi - lo > 1) {
      int mid = (lo + hi) >> 1;
      if (lofs[mid] <= j) lo = mid; else hi = mid;
    }
    strm[basel[lo] + (j - lofs[lo])] = lsort[j];
  }
}

// kD: fine sort within bucket.
__global__ __launch_bounds__(TB) void kD(
    const int* __restrict__ gcount, const int* __restrict__ gbase,
    const unsigned* __restrict__ strm, int* __restrict__ rowptr,
    int* __restrict__ col) {
  __shared__ int cnt[256];
  __shared__ int cur[256];
  __shared__ int sd[256];
  int b = blockIdx.x, tid = threadIdx.x;
  int base = gbase[b], n = gcount[b];
  if (tid < 256) cnt[tid] = 0;
  __syncthreads();
  unsigned wc[KD_SL];
#pragma unroll
  for (int j = 0; j < KD_SL; ++j) {
    int i = tid + j * TB;
    if (i < n) {
      unsigned w = strm[base + i];
      wc[j] = w;
      atomicAdd(&cnt[w >> 17], 1);
    }
  }
  for (int i = tid + KD_SL * TB; i < n; i += TB)     // overflow (~never)
    atomicAdd(&cnt[strm[base + i] >> 17], 1);
  __syncthreads();
  int v = (tid < 256) ? cnt[tid] : 0;
  if (tid < 256) sd[tid] = v;
  __syncthreads();
  for (int off = 1; off < 256; off <<= 1) {
    int t = (tid >= off && tid < 256) ? sd[tid - off] : 0;
    __syncthreads();
    if (tid < 256) sd[tid] += t;
    __syncthreads();
  }
  if (tid < 256) {
    int excl = sd[tid] - v;
    cur[tid] = excl;
    int node = (b << 8) + tid;
    if (node < NN) rowptr[node] = base + excl;
  }
  __syncthreads();
#pragma unroll
  for (int j = 0; j < KD_SL; ++j) {
    int i = tid + j * TB;
    if (i < n) {
      unsigned w = wc[j];
      int p = atomicAdd(&cur[w >> 17], 1);
      col[base + p] = (int)(w & 0x1FFFFu);
    }
  }
  for (int i = tid + KD_SL * TB; i < n; i += TB) {   // overflow (~never)
    unsigned w = strm[base + i];
    int p = atomicAdd(&cur[w >> 17], 1);
    col[base + p] = (int)(w & 0x1FFFFu);
  }
}

// ---- node sort by degree (counting sort, 256 clamped bins) -----------------
// Waves then hold equal-degree node groups -> kills E[max of 8 Poisson(32)]
// lockstep divergence in k_prop (~30% lane-time waste).
__global__ __launch_bounds__(1024) void kS1(
    const int* __restrict__ rowptr, int* __restrict__ dhist) {
  __shared__ int h[256];
  int tid = threadIdx.x;
  if (tid < 256) h[tid] = 0;
  __syncthreads();
  int node = blockIdx.x * 1024 + tid;
  if (node < NN) {
    int deg = rowptr[node + 1] - rowptr[node];
    atomicAdd(&h[min(deg, 255)], 1);
  }
  __syncthreads();
  if (tid < 256 && h[tid]) atomicAdd(&dhist[tid], h[tid]);
}

__global__ __launch_bounds__(256) void kS2(
    const int* __restrict__ dhist, int* __restrict__ dcur) {
  __shared__ int sd[256];
  int tid = threadIdx.x;
  int v = dhist[tid];
  sd[tid] = v;
  __syncthreads();
  for (int off = 1; off < 256; off <<= 1) {
    int t = (tid >= off) ? sd[tid - off] : 0;
    __syncthreads();
    sd[tid] += t;
    __syncthreads();
  }
  dcur[tid] = sd[tid] - v;                 // exclusive base = cursor
}

__global__ __launch_bounds__(1024) void kS3(
    const int* __restrict__ rowptr, int* __restrict__ dcur,
    int* __restrict__ nodeord) {
  __shared__ int h[256];
  __shared__ int basel[256];
  int tid = threadIdx.x;
  if (tid < 256) h[tid] = 0;
  __syncthreads();
  int node = blockIdx.x * 1024 + tid;
  int bin = -1;
  if (node < NN) {
    int deg = rowptr[node + 1] - rowptr[node];
    bin = min(deg, 255);
    atomicAdd(&h[bin], 1);
  }
  __syncthreads();
  if (tid < 256) {
    int c = h[tid];
    basel[tid] = c ? atomicAdd(&dcur[tid], c) : 0;
    h[tid] = 0;
  }
  __syncthreads();
  if (node < NN) {
    int off = atomicAdd(&h[bin], 1);
    nodeord[basel[bin] + off] = node;
  }
}

// ---- fused AGNN prop: 8 lanes/node, degree-sorted order, 8-wide prefetch ---
#define PROP_COMPUTE4(c0, c1, c2, c3, j0, j1, j2, j3)                        \
  {                                                                          \
    float r0 = dot2f(xdn2, c0);                                              \
    float r1 = dot2f(xdn2, c1);                                              \
    float r2 = dot2f(xdn2, c2);                                              \
    float r3 = dot2f(xdn2, c3);                                              \
    r0 += __shfl_xor(r0, 1); r1 += __shfl_xor(r1, 1);                        \
    r2 += __shfl_xor(r2, 1); r3 += __shfl_xor(r3, 1);                        \
    r0 += __shfl_xor(r0, 2); r1 += __shfl_xor(r1, 2);                        \
    r2 += __shfl_xor(r2, 2); r3 += __shfl_xor(r3, 2);                        \
    r0 += __shfl_xor(r0, 4); r1 += __shfl_xor(r1, 4);                        \
    r2 += __shfl_xor(r2, 4); r3 += __shfl_xor(r3, 4);                        \
    float e0 = __expf(beta * r0 * j0);                                       \
    float e1 = __expf(beta * r1 * j1);                                       \
    float e2v = __expf(beta * r2 * j2);                                      \
    float e3 = __expf(beta * r3 * j3);                                       \
    s += (e0 + e1) + (e2v + e3);                                             \
    a0 = fmaf(e0, (float)c0.x, a0);  a1 = fmaf(e0, (float)c0.y, a1);         \
    a0 = fmaf(e1, (float)c1.x, a0);  a1 = fmaf(e1, (float)c1.y, a1);         \
    a0 = fmaf(e2v, (float)c2.x, a0); a1 = fmaf(e2v, (float)c2.y, a1);        \
    a0 = fmaf(e3, (float)c3.x, a0);  a1 = fmaf(e3, (float)c3.y, a1);         \
  }

#define PROP_LOAD8(base_e)                                                   \
  {                                                                          \
    int u0 = col[(base_e)];     int u1 = col[(base_e) + 1];                  \
    int u2 = col[(base_e) + 2]; int u3 = col[(base_e) + 3];                  \
    int u4 = col[(base_e) + 4]; int u5 = col[(base_e) + 5];                  \
    int u6 = col[(base_e) + 6]; int u7 = col[(base_e) + 7];                  \
    f0 = H[u0 * 8 + l]; f1 = H[u1 * 8 + l];                                  \
    f2 = H[u2 * 8 + l]; f3 = H[u3 * 8 + l];                                  \
    f4 = H[u4 * 8 + l]; f5 = H[u5 * 8 + l];                                  \
    f6 = H[u6 * 8 + l]; f7 = H[u7 * 8 + l];                                  \
    i0 = invn[u0]; i1 = invn[u1]; i2 = invn[u2]; i3 = invn[u3];              \
    i4 = invn[u4]; i5 = invn[u5]; i6 = invn[u6]; i7 = invn[u7];              \
  }

__global__ __launch_bounds__(256) void k_prop(
    const int* __restrict__ nodeord,
    const int* __restrict__ rowptr, const int* __restrict__ col,
    const hf* __restrict__ hx, const float* __restrict__ invn,
    const float* __restrict__ beta_p,
    hf* __restrict__ hxo, float* __restrict__ invno) {
  int gid = blockIdx.x * 32 + (threadIdx.x >> 3);
  int l = threadIdx.x & 7;                 // lane owns features 2l, 2l+1
  if (gid >= NN) return;
  int node = nodeord[gid];                 // degree-sorted schedule
  float beta = beta_p ? beta_p[0] : 1.0f;
  const hf2* H = (const hf2*)hx;
  hf2 xi2 = H[node * 8 + l];
  float x0 = (float)xi2.x, x1 = (float)xi2.y;
  float invi = invn[node];
  float n2 = x0 * x0 + x1 * x1;
  n2 += __shfl_xor(n2, 1); n2 += __shfl_xor(n2, 2); n2 += __shfl_xor(n2, 4);
  hf2 xdn2; xdn2.x = (hf)(x0 * invi); xdn2.y = (hf)(x1 * invi);
  float dself = n2 * invi * invi;          // ||xn_i||^2
  float es = __expf(beta * dself);
  float s = es;
  float a0 = es * x0, a1 = es * x1;        // acc (2 features per lane)
  int e = rowptr[node], e2 = rowptr[node + 1];
  hf2 f0, f1, f2, f3, f4, f5, f6, f7;
  float i0, i1, i2, i3, i4, i5, i6, i7;
  if (e + 8 <= e2) PROP_LOAD8(e);          // prologue: load group 0
  for (; e + 16 <= e2; e += 8) {           // steady: consume 8, prefetch 8
    hf2 c0 = f0, c1 = f1, c2 = f2, c3 = f3, c4 = f4, c5 = f5, c6 = f6, c7 = f7;
    float j0 = i0, j1 = i1, j2 = i2, j3 = i3, j4 = i4, j5 = i5, j6 = i6, j7 = i7;
    PROP_LOAD8(e + 8);
    PROP_COMPUTE4(c0, c1, c2, c3, j0, j1, j2, j3);
    PROP_COMPUTE4(c4, c5, c6, c7, j4, j5, j6, j7);
  }
  if (e + 8 <= e2) {                       // drain pipelined group
    PROP_COMPUTE4(f0, f1, f2, f3, i0, i1, i2, i3);
    PROP_COMPUTE4(f4, f5, f6, f7, i4, i5, i6, i7);
    e += 8;
  }
  if (e + 4 <= e2) {                       // 4-wide remainder
    int u0 = col[e], u1 = col[e + 1], u2 = col[e + 2], u3 = col[e + 3];
    hf2 c0 = H[u0 * 8 + l], c1 = H[u1 * 8 + l];
    hf2 c2 = H[u2 * 8 + l], c3 = H[u3 * 8 + l];
    float j0 = invn[u0], j1 = invn[u1], j2 = invn[u2], j3 = invn[u3];
    PROP_COMPUTE4(c0, c1, c2, c3, j0, j1, j2, j3);
    e += 4;
  }
  for (; e < e2; ++e) {                    // tail singles
    int u = col[e];
    hf2 b = H[u * 8 + l];
    float r = dot2f(xdn2, b);
    r += __shfl_xor(r, 1); r += __shfl_xor(r, 2); r += __shfl_xor(r, 4);
    float ee = __expf(beta * r * invn[u]);
    s += ee;
    a0 = fmaf(ee, (float)b.x, a0); a1 = fmaf(ee, (float)b.y, a1);
  }
  float inv_s = 1.0f / s;
  hf2 o; o.x = (hf)(a0 * inv_s); o.y = (hf)(a1 * inv_s);
  float g0 = (float)o.x, g1 = (float)o.y;
  float m2 = g0 * g0 + g1 * g1;
  m2 += __shfl_xor(m2, 1); m2 += __shfl_xor(m2, 2); m2 += __shfl_xor(m2, 4);
  ((hf2*)hxo)[node * 8 + l] = o;
  if (l == 0) invno[node] = rsqrtf(fmaxf(m2, 1e-24f));
}

// ---------------- classifier + log_softmax (fp16 input) ---------------------
__global__ __launch_bounds__(256) void k_cls(
    const hf* __restrict__ x, const float* __restrict__ W2,
    const float* __restrict__ b2, float* __restrict__ out) {
  __shared__ float sW[HID * NCLS];
  __shared__ float sb[NCLS];
  for (int i = threadIdx.x; i < HID * NCLS; i += 256) sW[i] = W2[i];
  if (threadIdx.x < NCLS) sb[threadIdx.x] = b2[threadIdx.x];
  __syncthreads();
  int i = blockIdx.x * 256 + threadIdx.x;
  if (i >= NN) return;
  float xi[HID];
  const hf2* X = (const hf2*)(x + (size_t)i * HID);
#pragma unroll
  for (int r = 0; r < 8; ++r) {
    hf2 v = X[r];
    xi[2 * r] = (float)v.x; xi[2 * r + 1] = (float)v.y;
  }
  float logit[NCLS];
  float mx = -1e30f;
#pragma unroll
  for (int c = 0; c < NCLS; ++c) {
    float acc = sb[c];
#pragma unroll
    for (int kk = 0; kk < HID; ++kk) acc = fmaf(xi[kk], sW[kk * NCLS + c], acc);
    logit[c] = acc;
    mx = fmaxf(mx, acc);
  }
  float ssum = 0.0f;
#pragma unroll
  for (int c = 0; c < NCLS; ++c) ssum += __expf(logit[c] - mx);
  float lse = mx + logf(ssum);
  float* o = out + (size_t)i * NCLS;
#pragma unroll
  for (int c = 0; c < NCLS; ++c) o[c] = logit[c] - lse;
}

extern "C" void kernel_launch(void* const* d_in, const int* in_sizes, int n_in,
                              void* d_out, int out_size, void* d_ws, size_t ws_size,
                              hipStream_t stream) {
  const int*   x_ids = (const int*)d_in[0];
  const int*   ei    = (const int*)d_in[1];   // [2, E]: row0 = src, row1 = dst
  const float* emb   = (const float*)d_in[2];
  const float* W1    = (const float*)d_in[3];
  const float* b1    = (const float*)d_in[4];
  const float* beta2 = (const float*)d_in[5];
  const float* W2    = (const float*)d_in[6];
  const float* b2    = (const float*)d_in[7];
  float* out = (float*)d_out;

  // workspace: [strm NE u32 | col NE | rowptr | gcount | gbase | gcur | dhist | dcur]
  // strm dead after kD; fp16 pipeline + nodeord alias it (7.6 MB < 12.8 MB).
  unsigned* strm = (unsigned*)d_ws;
  int* col    = (int*)d_ws + NE;
  int* rowptr = col + NE;
  int* gcount = rowptr + (NN + 1);
  int* gbase  = gcount + NBKT;
  int* gcur   = gbase + NBKT;
  int* dhist  = gcur + NBKT;                     // [256]
  int* dcur   = dhist + 256;                     // [256]
  hf*    hx0   = (hf*)d_ws;                      // [NN*HID] 3.2 MB
  hf*    hx1   = hx0 + (size_t)NN * HID;         // [NN*HID] 3.2 MB
  float* invn0 = (float*)(hx1 + (size_t)NN * HID);   // [NN] 0.4 MB
  float* invn1 = invn0 + NN;                     // [NN] 0.4 MB
  int*   nodeord = (int*)(invn1 + NN);           // [NN] 0.4 MB (strm alias)

  const int* esrc = ei;
  const int* edst = ei + NE;

  const int gN = (NN + 255) / 256;
  const int gM = (NN + 15) / 16;
  const int gP = (NN + 31) / 32;

  // CSR build (self-loops handled analytically in k_prop)
  k_zero<<<2, 256, 0, stream>>>(gcount, NBKT);
  k_zero<<<1, 256, 0, stream>>>(dhist, 256);
  kA<<<NBLKC, TB, 0, stream>>>(edst, gcount);
  kB<<<1, 512, 0, stream>>>(gcount, gbase, gcur, rowptr);
  kC<<<NBLKC, TB, 0, stream>>>(esrc, edst, gcur, strm);
  kD<<<NBKT, TB, 0, stream>>>(gcount, gbase, strm, rowptr, col);

  // degree-sorted node order (needs finalized rowptr from kD)
  kS1<<<NSB, 1024, 0, stream>>>(rowptr, dhist);
  kS2<<<1, 256, 0, stream>>>(dhist, dcur);
  kS3<<<NSB, 1024, 0, stream>>>(rowptr, dcur, nodeord);

  // features (fp16 + invn), aliasing strm (dead after kD)
  k_embed_mlp<<<gM, 256, 0, stream>>>(x_ids, emb, W1, b1, hx0, invn0);

  // prop1 (beta = 1.0), prop2 (beta = beta2)
  k_prop<<<gP, 256, 0, stream>>>(nodeord, rowptr, col, hx0, invn0, nullptr, hx1, invn1);
  k_prop<<<gP, 256, 0, stream>>>(nodeord, rowptr, col, hx1, invn1, beta2, hx0, invn0);

  k_cls<<<gN, 256, 0, stream>>>(hx0, W2, b2, out);
}

// Round 16
// 209.214 us; speedup vs baseline: 1.0000x; 1.0000x over previous
//
#include <hip/hip_runtime.h>
#include <math.h>

#define NN    100000
#define NE    3200000
#define FEAT  128
#define HID   16
#define NCLS  20
#define NBKT  391            // ceil(NN/256) coarse buckets (dst >> 8)
#define NBLKC 512            // blocks for bucket count/scatter
#define TB    1024           // threads/block for kA/kC/kD
#define CHNK  ((NE + NBLKC - 1) / NBLKC)   // 6250 edges per kC block
#define KC_SL 7              // ceil(CHNK/TB) register-cache slots
#define KD_SL 9              // 9*TB=9216 >= max coarse-bucket degree (~8.6K)

typedef _Float16 hf;
typedef _Float16 hf2 __attribute__((ext_vector_type(2)));

__device__ __forceinline__ float dot2f(hf2 a, hf2 b) {
#if defined(__has_builtin) && __has_builtin(__builtin_amdgcn_fdot2)
  return __builtin_amdgcn_fdot2(a, b, 0.0f, false);
#else
  return fmaf((float)a.y, (float)b.y, (float)a.x * (float)b.x);
#endif
}

// ---- embedding gather + MLP -> fp16 features + invn ------------------------
__global__ __launch_bounds__(256) void k_embed_mlp(
    const int* __restrict__ ids, const float* __restrict__ emb,
    const float* __restrict__ W1, const float* __restrict__ b1,
    hf* __restrict__ hx, float* __restrict__ invn) {
  __shared__ float sW[FEAT * HID];        // 8 KB
  __shared__ float sx[16][FEAT + 4];      // 16 staged rows, 132f stride
  for (int i = threadIdx.x; i < FEAT * HID; i += 256) sW[i] = W1[i];
  int node = blockIdx.x * 16 + (threadIdx.x >> 4);
  int nl = threadIdx.x >> 4;              // local node 0..15
  int k = threadIdx.x & 15;
  const float4* er = (const float4*)(emb + (size_t)ids[node] * FEAT);
  float4 ra = er[2 * k], rb = er[2 * k + 1];     // coalesced 32B/lane
  *(float4*)&sx[nl][8 * k] = ra;
  *(float4*)&sx[nl][8 * k + 4] = rb;
  __syncthreads();
  float acc = b1[k];
  const float* xr = sx[nl];
#pragma unroll
  for (int j = 0; j < FEAT; ++j) acc = fmaf(xr[j], sW[j * HID + k], acc);
  acc = fmaxf(acc, 0.0f);
  hf h = (hf)acc;
  float a = (float)h;
  float n2 = a * a;
  n2 += __shfl_xor(n2, 1); n2 += __shfl_xor(n2, 2);
  n2 += __shfl_xor(n2, 4); n2 += __shfl_xor(n2, 8);
  hx[node * HID + k] = h;
  if (k == 0) invn[node] = rsqrtf(fmaxf(n2, 1e-24f));  // 1/max(||x||,1e-12)
}

// ---------------- CSR build: bucketed counting sort -------------------------
__global__ __launch_bounds__(256) void k_zero(int* __restrict__ c, int n) {
  int i = blockIdx.x * 256 + threadIdx.x;
  if (i < n) c[i] = 0;
}

__global__ __launch_bounds__(TB) void kA(
    const int* __restrict__ edst, int* __restrict__ gcount) {
  __shared__ int h[NBKT];
  for (int i = threadIdx.x; i < NBKT; i += TB) h[i] = 0;
  __syncthreads();
  int s0 = blockIdx.x * CHNK, s1 = min(NE, s0 + CHNK);
  for (int i = s0 + threadIdx.x; i < s1; i += TB)
    atomicAdd(&h[__builtin_nontemporal_load(edst + i) >> 8], 1);
  __syncthreads();
  for (int i = threadIdx.x; i < NBKT; i += TB)
    if (h[i]) atomicAdd(&gcount[i], h[i]);
}

__global__ __launch_bounds__(512) void kB(
    const int* __restrict__ gcount, int* __restrict__ gbase,
    int* __restrict__ gcur, int* __restrict__ rowptr) {
  __shared__ int sd[512];
  int tid = threadIdx.x;
  int v = (tid < NBKT) ? gcount[tid] : 0;
  sd[tid] = v;
  __syncthreads();
  for (int off = 1; off < 512; off <<= 1) {
    int t = (tid >= off) ? sd[tid - off] : 0;
    __syncthreads();
    sd[tid] += t;
    __syncthreads();
  }
  if (tid < NBKT) { int b = sd[tid] - v; gbase[tid] = b; gcur[tid] = b; }
  if (tid == 0) rowptr[NN] = NE;
}

// kC: block-local LDS counting sort, COALESCED run write-out.
__global__ __launch_bounds__(TB) void kC(
    const int* __restrict__ esrc, const int* __restrict__ edst,
    int* __restrict__ gcur, unsigned* __restrict__ strm) {
  __shared__ int h[NBKT];            // counts, then scatter cursors
  __shared__ int lofs[NBKT + 1];     // local exclusive offsets
  __shared__ int basel[NBKT];        // reserved global run bases
  __shared__ int sd[512];
  __shared__ unsigned lsort[CHNK];   // 25 KB locally sorted chunk
  int tid = threadIdx.x;
  for (int i = tid; i < NBKT; i += TB) h[i] = 0;
  __syncthreads();
  int s0 = blockIdx.x * CHNK, s1 = min(NE, s0 + CHNK);
  int total = s1 - s0;
  int dc[KC_SL], sc[KC_SL];
#pragma unroll
  for (int j = 0; j < KC_SL; ++j) {
    int i = s0 + tid + j * TB;
    if (i < s1) {
      int d = __builtin_nontemporal_load(edst + i);
      dc[j] = d;
      sc[j] = __builtin_nontemporal_load(esrc + i);
      atomicAdd(&h[d >> 8], 1);
    }
  }
  __syncthreads();                                   // hist complete
  int v = (tid < NBKT) ? h[tid] : 0;
  if (tid < 512) sd[tid] = v;
  __syncthreads();
  for (int off = 1; off < 512; off <<= 1) {
    int t = (tid < 512 && tid >= off) ? sd[tid - off] : 0;
    __syncthreads();
    if (tid < 512) sd[tid] += t;
    __syncthreads();
  }
  if (tid < NBKT) {
    lofs[tid] = sd[tid] - v;
    basel[tid] = v ? atomicAdd(&gcur[tid], v) : 0;
  }
  if (tid == 0) lofs[NBKT] = total;
  __syncthreads();                                   // scan consumed
  for (int i = tid; i < NBKT; i += TB) h[i] = 0;     // cursors
  __syncthreads();
#pragma unroll
  for (int j = 0; j < KC_SL; ++j) {
    int i = s0 + tid + j * TB;
    if (i < s1) {
      int d = dc[j];
      int b = d >> 8;
      int p = lofs[b] + atomicAdd(&h[b], 1);
      lsort[p] = (unsigned)sc[j] | ((unsigned)(d & 255) << 17);
    }
  }
  __syncthreads();                                   // lsort ready
  for (int j = tid; j < total; j += TB) {
    int lo = 0, hi = NBKT;                           // lofs[lo]<=j<lofs[hi]
    while (hi - lo > 1) {
      int mid = (lo + hi) >> 1;
      if (lofs[mid] <= j) lo = mid; else hi = mid;
    }
    strm[basel[lo] + (j - lofs[lo])] = lsort[j];
  }
}

// kD: fine sort within bucket + WINDOW-LOCAL degree sort of its 256 nodes.
// (R15 lesson: global degree-sort broke col locality, FETCH 39->55MB. Sorting
// within the 256-node window keeps col reads inside one ~33KB L2-resident
// segment while still grouping equal-degree nodes into waves.)
__global__ __launch_bounds__(TB) void kD(
    const int* __restrict__ gcount, const int* __restrict__ gbase,
    const unsigned* __restrict__ strm, int* __restrict__ rowptr,
    int* __restrict__ col, int* __restrict__ nodeord) {
  __shared__ int cnt[256];
  __shared__ int cur[256];
  __shared__ int sd[256];
  __shared__ int dh[256];
  __shared__ int db[256];
  int b = blockIdx.x, tid = threadIdx.x;
  int base = gbase[b], n = gcount[b];
  if (tid < 256) { cnt[tid] = 0; dh[tid] = 0; }
  __syncthreads();
  unsigned wc[KD_SL];
#pragma unroll
  for (int j = 0; j < KD_SL; ++j) {
    int i = tid + j * TB;
    if (i < n) {
      unsigned w = strm[base + i];
      wc[j] = w;
      atomicAdd(&cnt[w >> 17], 1);
    }
  }
  for (int i = tid + KD_SL * TB; i < n; i += TB)     // overflow (~never)
    atomicAdd(&cnt[strm[base + i] >> 17], 1);
  __syncthreads();
  int v = (tid < 256) ? cnt[tid] : 0;
  if (tid < 256) sd[tid] = v;
  __syncthreads();
  for (int off = 1; off < 256; off <<= 1) {
    int t = (tid >= off && tid < 256) ? sd[tid - off] : 0;
    __syncthreads();
    if (tid < 256) sd[tid] += t;
    __syncthreads();
  }
  if (tid < 256) {
    int excl = sd[tid] - v;
    cur[tid] = excl;
    int node = (b << 8) + tid;
    if (node < NN) rowptr[node] = base + excl;
  }
  __syncthreads();
#pragma unroll
  for (int j = 0; j < KD_SL; ++j) {
    int i = tid + j * TB;
    if (i < n) {
      unsigned w = wc[j];
      int p = atomicAdd(&cur[w >> 17], 1);
      col[base + p] = (int)(w & 0x1FFFFu);
    }
  }
  for (int i = tid + KD_SL * TB; i < n; i += TB) {   // overflow (~never)
    unsigned w = strm[base + i];
    int p = atomicAdd(&cur[w >> 17], 1);
    col[base + p] = (int)(w & 0x1FFFFu);
  }
  // ---- window-local degree sort (cnt[tid] = degree of node (b<<8)+tid) ----
  int nvalid = min(256, NN - (b << 8));
  int bin = 0;
  if (tid < nvalid) {
    bin = min(cnt[tid], 255);
    atomicAdd(&dh[bin], 1);
  }
  __syncthreads();
  int dv = (tid < 256) ? dh[tid] : 0;
  if (tid < 256) sd[tid] = dv;             // sd free after col-scatter barrier
  __syncthreads();
  for (int off = 1; off < 256; off <<= 1) {
    int t = (tid >= off && tid < 256) ? sd[tid - off] : 0;
    __syncthreads();
    if (tid < 256) sd[tid] += t;
    __syncthreads();
  }
  if (tid < 256) { db[tid] = sd[tid] - dv; dh[tid] = 0; }
  __syncthreads();
  if (tid < nvalid) {
    int pos = db[bin] + atomicAdd(&dh[bin], 1);
    nodeord[(b << 8) + pos] = (b << 8) + tid;
  }
}

// ---- fused AGNN prop: 8 lanes/node, window-degree-sorted, 8-wide prefetch --
#define PROP_COMPUTE4(c0, c1, c2, c3, j0, j1, j2, j3)                        \
  {                                                                          \
    float r0 = dot2f(xdn2, c0);                                              \
    float r1 = dot2f(xdn2, c1);                                              \
    float r2 = dot2f(xdn2, c2);                                              \
    float r3 = dot2f(xdn2, c3);                                              \
    r0 += __shfl_xor(r0, 1); r1 += __shfl_xor(r1, 1);                        \
    r2 += __shfl_xor(r2, 1); r3 += __shfl_xor(r3, 1);                        \
    r0 += __shfl_xor(r0, 2); r1 += __shfl_xor(r1, 2);                        \
    r2 += __shfl_xor(r2, 2); r3 += __shfl_xor(r3, 2);                        \
    r0 += __shfl_xor(r0, 4); r1 += __shfl_xor(r1, 4);                        \
    r2 += __shfl_xor(r2, 4); r3 += __shfl_xor(r3, 4);                        \
    float e0 = __expf(beta * r0 * j0);                                       \
    float e1 = __expf(beta * r1 * j1);                                       \
    float e2v = __expf(beta * r2 * j2);                                      \
    float e3 = __expf(beta * r3 * j3);                                       \
    s += (e0 + e1) + (e2v + e3);                                             \
    a0 = fmaf(e0, (float)c0.x, a0);  a1 = fmaf(e0, (float)c0.y, a1);         \
    a0 = fmaf(e1, (float)c1.x, a0);  a1 = fmaf(e1, (float)c1.y, a1);         \
    a0 = fmaf(e2v, (float)c2.x, a0); a1 = fmaf(e2v, (float)c2.y, a1);        \
    a0 = fmaf(e3, (float)c3.x, a0);  a1 = fmaf(e3, (float)c3.y, a1);         \
  }

#define PROP_LOAD8(base_e)                                                   \
  {                                                                          \
    int u0 = col[(base_e)];     int u1 = col[(base_e) + 1];                  \
    int u2 = col[(base_e) + 2]; int u3 = col[(base_e) + 3];                  \
    int u4 = col[(base_e) + 4]; int u5 = col[(base_e) + 5];                  \
    int u6 = col[(base_e) + 6]; int u7 = col[(base_e) + 7];                  \
    f0 = H[u0 * 8 + l]; f1 = H[u1 * 8 + l];                                  \
    f2 = H[u2 * 8 + l]; f3 = H[u3 * 8 + l];                                  \
    f4 = H[u4 * 8 + l]; f5 = H[u5 * 8 + l];                                  \
    f6 = H[u6 * 8 + l]; f7 = H[u7 * 8 + l];                                  \
    i0 = invn[u0]; i1 = invn[u1]; i2 = invn[u2]; i3 = invn[u3];              \
    i4 = invn[u4]; i5 = invn[u5]; i6 = invn[u6]; i7 = invn[u7];              \
  }

__global__ __launch_bounds__(256) void k_prop(
    const int* __restrict__ nodeord,
    const int* __restrict__ rowptr, const int* __restrict__ col,
    const hf* __restrict__ hx, const float* __restrict__ invn,
    const float* __restrict__ beta_p,
    hf* __restrict__ hxo, float* __restrict__ invno) {
  int gid = blockIdx.x * 32 + (threadIdx.x >> 3);
  int l = threadIdx.x & 7;                 // lane owns features 2l, 2l+1
  if (gid >= NN) return;
  int node = nodeord[gid];                 // window-local degree order
  float beta = beta_p ? beta_p[0] : 1.0f;
  const hf2* H = (const hf2*)hx;
  hf2 xi2 = H[node * 8 + l];
  float x0 = (float)xi2.x, x1 = (float)xi2.y;
  float invi = invn[node];
  float n2 = x0 * x0 + x1 * x1;
  n2 += __shfl_xor(n2, 1); n2 += __shfl_xor(n2, 2); n2 += __shfl_xor(n2, 4);
  hf2 xdn2; xdn2.x = (hf)(x0 * invi); xdn2.y = (hf)(x1 * invi);
  float dself = n2 * invi * invi;          // ||xn_i||^2
  float es = __expf(beta * dself);
  float s = es;
  float a0 = es * x0, a1 = es * x1;        // acc (2 features per lane)
  int e = rowptr[node], e2 = rowptr[node + 1];
  hf2 f0, f1, f2, f3, f4, f5, f6, f7;
  float i0, i1, i2, i3, i4, i5, i6, i7;
  if (e + 8 <= e2) PROP_LOAD8(e);          // prologue: load group 0
  for (; e + 16 <= e2; e += 8) {           // steady: consume 8, prefetch 8
    hf2 c0 = f0, c1 = f1, c2 = f2, c3 = f3, c4 = f4, c5 = f5, c6 = f6, c7 = f7;
    float j0 = i0, j1 = i1, j2 = i2, j3 = i3, j4 = i4, j5 = i5, j6 = i6, j7 = i7;
    PROP_LOAD8(e + 8);
    PROP_COMPUTE4(c0, c1, c2, c3, j0, j1, j2, j3);
    PROP_COMPUTE4(c4, c5, c6, c7, j4, j5, j6, j7);
  }
  if (e + 8 <= e2) {                       // drain pipelined group
    PROP_COMPUTE4(f0, f1, f2, f3, i0, i1, i2, i3);
    PROP_COMPUTE4(f4, f5, f6, f7, i4, i5, i6, i7);
    e += 8;
  }
  if (e + 4 <= e2) {                       // 4-wide remainder
    int u0 = col[e], u1 = col[e + 1], u2 = col[e + 2], u3 = col[e + 3];
    hf2 c0 = H[u0 * 8 + l], c1 = H[u1 * 8 + l];
    hf2 c2 = H[u2 * 8 + l], c3 = H[u3 * 8 + l];
    float j0 = invn[u0], j1 = invn[u1], j2 = invn[u2], j3 = invn[u3];
    PROP_COMPUTE4(c0, c1, c2, c3, j0, j1, j2, j3);
    e += 4;
  }
  for (; e < e2; ++e) {                    // tail singles
    int u = col[e];
    hf2 b = H[u * 8 + l];
    float r = dot2f(xdn2, b);
    r += __shfl_xor(r, 1); r += __shfl_xor(r, 2); r += __shfl_xor(r, 4);
    float ee = __expf(beta * r * invn[u]);
    s += ee;
    a0 = fmaf(ee, (float)b.x, a0); a1 = fmaf(ee, (float)b.y, a1);
  }
  float inv_s = 1.0f / s;
  hf2 o; o.x = (hf)(a0 * inv_s); o.y = (hf)(a1 * inv_s);
  float g0 = (float)o.x, g1 = (float)o.y;
  float m2 = g0 * g0 + g1 * g1;
  m2 += __shfl_xor(m2, 1); m2 += __shfl_xor(m2, 2); m2 += __shfl_xor(m2, 4);
  ((hf2*)hxo)[node * 8 + l] = o;
  if (l == 0) invno[node] = rsqrtf(fmaxf(m2, 1e-24f));
}

// ---------------- classifier + log_softmax (fp16 input) ---------------------
__global__ __launch_bounds__(256) void k_cls(
    const hf* __restrict__ x, const float* __restrict__ W2,
    const float* __restrict__ b2, float* __restrict__ out) {
  __shared__ float sW[HID * NCLS];
  __shared__ float sb[NCLS];
  for (int i = threadIdx.x; i < HID * NCLS; i += 256) sW[i] = W2[i];
  if (threadIdx.x < NCLS) sb[threadIdx.x] = b2[threadIdx.x];
  __syncthreads();
  int i = blockIdx.x * 256 + threadIdx.x;
  if (i >= NN) return;
  float xi[HID];
  const hf2* X = (const hf2*)(x + (size_t)i * HID);
#pragma unroll
  for (int r = 0; r < 8; ++r) {
    hf2 v = X[r];
    xi[2 * r] = (float)v.x; xi[2 * r + 1] = (float)v.y;
  }
  float logit[NCLS];
  float mx = -1e30f;
#pragma unroll
  for (int c = 0; c < NCLS; ++c) {
    float acc = sb[c];
#pragma unroll
    for (int kk = 0; kk < HID; ++kk) acc = fmaf(xi[kk], sW[kk * NCLS + c], acc);
    logit[c] = acc;
    mx = fmaxf(mx, acc);
  }
  float ssum = 0.0f;
#pragma unroll
  for (int c = 0; c < NCLS; ++c) ssum += __expf(logit[c] - mx);
  float lse = mx + logf(ssum);
  float* o = out + (size_t)i * NCLS;
#pragma unroll
  for (int c = 0; c < NCLS; ++c) o[c] = logit[c] - lse;
}

extern "C" void kernel_launch(void* const* d_in, const int* in_sizes, int n_in,
                              void* d_out, int out_size, void* d_ws, size_t ws_size,
                              hipStream_t stream) {
  const int*   x_ids = (const int*)d_in[0];
  const int*   ei    = (const int*)d_in[1];   // [2, E]: row0 = src, row1 = dst
  const float* emb   = (const float*)d_in[2];
  const float* W1    = (const float*)d_in[3];
  const float* b1    = (const float*)d_in[4];
  const float* beta2 = (const float*)d_in[5];
  const float* W2    = (const float*)d_in[6];
  const float* b2    = (const float*)d_in[7];
  float* out = (float*)d_out;

  // workspace: [strm NE u32 | col NE | rowptr | gcount | gbase | gcur]
  // strm dead after kD; fp16 pipeline + nodeord alias it (7.6 MB < 12.8 MB).
  unsigned* strm = (unsigned*)d_ws;
  int* col    = (int*)d_ws + NE;
  int* rowptr = col + NE;
  int* gcount = rowptr + (NN + 1);
  int* gbase  = gcount + NBKT;
  int* gcur   = gbase + NBKT;
  hf*    hx0   = (hf*)d_ws;                      // [NN*HID] 3.2 MB
  hf*    hx1   = hx0 + (size_t)NN * HID;         // [NN*HID] 3.2 MB
  float* invn0 = (float*)(hx1 + (size_t)NN * HID);   // [NN] 0.4 MB
  float* invn1 = invn0 + NN;                     // [NN] 0.4 MB
  int*   nodeord = (int*)(invn1 + NN);           // [NN] 0.4 MB (strm alias)
  // NOTE: nodeord overlaps strm tail region? strm is [0, 12.8MB); fp16 pipeline
  // occupies [0, 7.2MB); nodeord at [7.2, 7.6MB) — still inside strm. kD writes
  // nodeord AFTER its last strm read of that region? No: kD reads strm[base..]
  // throughout. nodeord must NOT alias strm -> place it after gcur instead.
  (void)nodeord;
  int* nodeord2 = gcur + NBKT;                   // [NN] safe: beyond all aliases

  const int* esrc = ei;
  const int* edst = ei + NE;

  const int gN = (NN + 255) / 256;
  const int gM = (NN + 15) / 16;
  const int gP = (NN + 31) / 32;

  // CSR build (self-loops handled analytically in k_prop)
  k_zero<<<2, 256, 0, stream>>>(gcount, NBKT);
  kA<<<NBLKC, TB, 0, stream>>>(edst, gcount);
  kB<<<1, 512, 0, stream>>>(gcount, gbase, gcur, rowptr);
  kC<<<NBLKC, TB, 0, stream>>>(esrc, edst, gcur, strm);
  kD<<<NBKT, TB, 0, stream>>>(gcount, gbase, strm, rowptr, col, nodeord2);

  // features (fp16 + invn), aliasing strm (dead after kD)
  k_embed_mlp<<<gM, 256, 0, stream>>>(x_ids, emb, W1, b1, hx0, invn0);

  // prop1 (beta = 1.0), prop2 (beta = beta2)
  k_prop<<<gP, 256, 0, stream>>>(nodeord2, rowptr, col, hx0, invn0, nullptr, hx1, invn1);
  k_prop<<<gP, 256, 0, stream>>>(nodeord2, rowptr, col, hx1, invn1, beta2, hx0, invn0);

  k_cls<<<gN, 256, 0, stream>>>(hx0, W2, b2, out);
}

// Round 17
// 187.938 us; speedup vs baseline: 1.1132x; 1.1132x over previous
//
#include <hip/hip_runtime.h>
#include <math.h>

#define NN    100000
#define NE    3200000
#define FEAT  128
#define HID   16
#define NCLS  20
#define NBKT  391            // ceil(NN/256) coarse buckets (dst >> 8)
#define NBLKC 512            // blocks for bucket count/scatter
#define TB    1024           // threads/block for kA/kC/kD
#define CHNK  ((NE + NBLKC - 1) / NBLKC)   // 6250 edges per kC block
#define KC_SL 7              // ceil(CHNK/TB) register-cache slots
#define KD_SL 9              // 9*TB=9216 >= max coarse-bucket degree (~8.6K)

typedef _Float16 hf;
typedef _Float16 hf2 __attribute__((ext_vector_type(2)));

__device__ __forceinline__ float dot2f(hf2 a, hf2 b) {
#if defined(__has_builtin) && __has_builtin(__builtin_amdgcn_fdot2)
  return __builtin_amdgcn_fdot2(a, b, 0.0f, false);
#else
  return fmaf((float)a.y, (float)b.y, (float)a.x * (float)b.x);
#endif
}

// ---- embedding gather + MLP -> fp16 features + invn ------------------------
__global__ __launch_bounds__(256) void k_embed_mlp(
    const int* __restrict__ ids, const float* __restrict__ emb,
    const float* __restrict__ W1, const float* __restrict__ b1,
    hf* __restrict__ hx, float* __restrict__ invn) {
  __shared__ float sW[FEAT * HID];        // 8 KB
  __shared__ float sx[16][FEAT + 4];      // 16 staged rows, 132f stride
  for (int i = threadIdx.x; i < FEAT * HID; i += 256) sW[i] = W1[i];
  int node = blockIdx.x * 16 + (threadIdx.x >> 4);
  int nl = threadIdx.x >> 4;              // local node 0..15
  int k = threadIdx.x & 15;
  const float4* er = (const float4*)(emb + (size_t)ids[node] * FEAT);
  float4 ra = er[2 * k], rb = er[2 * k + 1];     // coalesced 32B/lane
  *(float4*)&sx[nl][8 * k] = ra;
  *(float4*)&sx[nl][8 * k + 4] = rb;
  __syncthreads();
  float acc = b1[k];
  const float* xr = sx[nl];
#pragma unroll
  for (int j = 0; j < FEAT; ++j) acc = fmaf(xr[j], sW[j * HID + k], acc);
  acc = fmaxf(acc, 0.0f);
  hf h = (hf)acc;
  float a = (float)h;
  float n2 = a * a;
  n2 += __shfl_xor(n2, 1); n2 += __shfl_xor(n2, 2);
  n2 += __shfl_xor(n2, 4); n2 += __shfl_xor(n2, 8);
  hx[node * HID + k] = h;
  if (k == 0) invn[node] = rsqrtf(fmaxf(n2, 1e-24f));  // 1/max(||x||,1e-12)
}

// ---------------- CSR build: bucketed counting sort -------------------------
__global__ __launch_bounds__(256) void k_zero(int* __restrict__ c, int n) {
  int i = blockIdx.x * 256 + threadIdx.x;
  if (i < n) c[i] = 0;
}

__global__ __launch_bounds__(TB) void kA(
    const int* __restrict__ edst, int* __restrict__ gcount) {
  __shared__ int h[NBKT];
  for (int i = threadIdx.x; i < NBKT; i += TB) h[i] = 0;
  __syncthreads();
  int s0 = blockIdx.x * CHNK, s1 = min(NE, s0 + CHNK);
  for (int i = s0 + threadIdx.x; i < s1; i += TB)
    atomicAdd(&h[__builtin_nontemporal_load(edst + i) >> 8], 1);
  __syncthreads();
  for (int i = threadIdx.x; i < NBKT; i += TB)
    if (h[i]) atomicAdd(&gcount[i], h[i]);
}

__global__ __launch_bounds__(512) void kB(
    const int* __restrict__ gcount, int* __restrict__ gbase,
    int* __restrict__ gcur, int* __restrict__ rowptr) {
  __shared__ int sd[512];
  int tid = threadIdx.x;
  int v = (tid < NBKT) ? gcount[tid] : 0;
  sd[tid] = v;
  __syncthreads();
  for (int off = 1; off < 512; off <<= 1) {
    int t = (tid >= off) ? sd[tid - off] : 0;
    __syncthreads();
    sd[tid] += t;
    __syncthreads();
  }
  if (tid < NBKT) { int b = sd[tid] - v; gbase[tid] = b; gcur[tid] = b; }
  if (tid == 0) rowptr[NN] = NE;
}

// kC: block-local LDS counting sort, COALESCED run write-out.
// R17: write-out bucket found via uint16 lookup table filled during the LDS
// scatter (2 dependent LDS loads) instead of a 9-deep binary search over lofs.
__global__ __launch_bounds__(TB) void kC(
    const int* __restrict__ esrc, const int* __restrict__ edst,
    int* __restrict__ gcur, unsigned* __restrict__ strm) {
  __shared__ int h[NBKT];            // counts, then scatter cursors
  __shared__ int lofs[NBKT + 1];     // local exclusive offsets
  __shared__ int basel[NBKT];        // reserved global run bases
  __shared__ int sd[512];
  __shared__ unsigned lsort[CHNK];   // 25 KB locally sorted chunk
  __shared__ unsigned short bkt[CHNK];   // 12.5 KB bucket id per slot
  int tid = threadIdx.x;
  for (int i = tid; i < NBKT; i += TB) h[i] = 0;
  __syncthreads();
  int s0 = blockIdx.x * CHNK, s1 = min(NE, s0 + CHNK);
  int total = s1 - s0;
  int dc[KC_SL], sc[KC_SL];
#pragma unroll
  for (int j = 0; j < KC_SL; ++j) {
    int i = s0 + tid + j * TB;
    if (i < s1) {
      int d = __builtin_nontemporal_load(edst + i);
      dc[j] = d;
      sc[j] = __builtin_nontemporal_load(esrc + i);
      atomicAdd(&h[d >> 8], 1);
    }
  }
  __syncthreads();                                   // hist complete
  int v = (tid < NBKT) ? h[tid] : 0;
  if (tid < 512) sd[tid] = v;
  __syncthreads();
  for (int off = 1; off < 512; off <<= 1) {
    int t = (tid < 512 && tid >= off) ? sd[tid - off] : 0;
    __syncthreads();
    if (tid < 512) sd[tid] += t;
    __syncthreads();
  }
  if (tid < NBKT) {
    lofs[tid] = sd[tid] - v;
    basel[tid] = v ? atomicAdd(&gcur[tid], v) : 0;
  }
  if (tid == 0) lofs[NBKT] = total;
  __syncthreads();                                   // scan consumed
  for (int i = tid; i < NBKT; i += TB) h[i] = 0;     // cursors
  __syncthreads();
#pragma unroll
  for (int j = 0; j < KC_SL; ++j) {
    int i = s0 + tid + j * TB;
    if (i < s1) {
      int d = dc[j];
      int b = d >> 8;
      int p = lofs[b] + atomicAdd(&h[b], 1);
      lsort[p] = (unsigned)sc[j] | ((unsigned)(d & 255) << 17);
      bkt[p] = (unsigned short)b;
    }
  }
  __syncthreads();                                   // lsort+bkt ready
  for (int j = tid; j < total; j += TB) {
    int b = bkt[j];
    strm[basel[b] + (j - lofs[b])] = lsort[j];
  }
}

// kD: fine sort within bucket.
__global__ __launch_bounds__(TB) void kD(
    const int* __restrict__ gcount, const int* __restrict__ gbase,
    const unsigned* __restrict__ strm, int* __restrict__ rowptr,
    int* __restrict__ col) {
  __shared__ int cnt[256];
  __shared__ int cur[256];
  __shared__ int sd[256];
  int b = blockIdx.x, tid = threadIdx.x;
  int base = gbase[b], n = gcount[b];
  if (tid < 256) cnt[tid] = 0;
  __syncthreads();
  unsigned wc[KD_SL];
#pragma unroll
  for (int j = 0; j < KD_SL; ++j) {
    int i = tid + j * TB;
    if (i < n) {
      unsigned w = strm[base + i];
      wc[j] = w;
      atomicAdd(&cnt[w >> 17], 1);
    }
  }
  for (int i = tid + KD_SL * TB; i < n; i += TB)     // overflow (~never)
    atomicAdd(&cnt[strm[base + i] >> 17], 1);
  __syncthreads();
  int v = (tid < 256) ? cnt[tid] : 0;
  if (tid < 256) sd[tid] = v;
  __syncthreads();
  for (int off = 1; off < 256; off <<= 1) {
    int t = (tid >= off && tid < 256) ? sd[tid - off] : 0;
    __syncthreads();
    if (tid < 256) sd[tid] += t;
    __syncthreads();
  }
  if (tid < 256) {
    int excl = sd[tid] - v;
    cur[tid] = excl;
    int node = (b << 8) + tid;
    if (node < NN) rowptr[node] = base + excl;
  }
  __syncthreads();
#pragma unroll
  for (int j = 0; j < KD_SL; ++j) {
    int i = tid + j * TB;
    if (i < n) {
      unsigned w = wc[j];
      int p = atomicAdd(&cur[w >> 17], 1);
      col[base + p] = (int)(w & 0x1FFFFu);
    }
  }
  for (int i = tid + KD_SL * TB; i < n; i += TB) {   // overflow (~never)
    unsigned w = strm[base + i];
    int p = atomicAdd(&cur[w >> 17], 1);
    col[base + p] = (int)(w & 0x1FFFFu);
  }
}

// ---- fused AGNN prop: 8 lanes/node, fdot2, 8-wide + depth-1 prefetch -------
// (converged: 44us = random-gather latency floor; R12/R13/R15/R16 all flat/neg)
#define PROP_COMPUTE4(c0, c1, c2, c3, j0, j1, j2, j3)                        \
  {                                                                          \
    float r0 = dot2f(xdn2, c0);                                              \
    float r1 = dot2f(xdn2, c1);                                              \
    float r2 = dot2f(xdn2, c2);                                              \
    float r3 = dot2f(xdn2, c3);                                              \
    r0 += __shfl_xor(r0, 1); r1 += __shfl_xor(r1, 1);                        \
    r2 += __shfl_xor(r2, 1); r3 += __shfl_xor(r3, 1);                        \
    r0 += __shfl_xor(r0, 2); r1 += __shfl_xor(r1, 2);                        \
    r2 += __shfl_xor(r2, 2); r3 += __shfl_xor(r3, 2);                        \
    r0 += __shfl_xor(r0, 4); r1 += __shfl_xor(r1, 4);                        \
    r2 += __shfl_xor(r2, 4); r3 += __shfl_xor(r3, 4);                        \
    float e0 = __expf(beta * r0 * j0);                                       \
    float e1 = __expf(beta * r1 * j1);                                       \
    float e2v = __expf(beta * r2 * j2);                                      \
    float e3 = __expf(beta * r3 * j3);                                       \
    s += (e0 + e1) + (e2v + e3);                                             \
    a0 = fmaf(e0, (float)c0.x, a0);  a1 = fmaf(e0, (float)c0.y, a1);         \
    a0 = fmaf(e1, (float)c1.x, a0);  a1 = fmaf(e1, (float)c1.y, a1);         \
    a0 = fmaf(e2v, (float)c2.x, a0); a1 = fmaf(e2v, (float)c2.y, a1);        \
    a0 = fmaf(e3, (float)c3.x, a0);  a1 = fmaf(e3, (float)c3.y, a1);         \
  }

#define PROP_LOAD8(base_e)                                                   \
  {                                                                          \
    int u0 = col[(base_e)];     int u1 = col[(base_e) + 1];                  \
    int u2 = col[(base_e) + 2]; int u3 = col[(base_e) + 3];                  \
    int u4 = col[(base_e) + 4]; int u5 = col[(base_e) + 5];                  \
    int u6 = col[(base_e) + 6]; int u7 = col[(base_e) + 7];                  \
    f0 = H[u0 * 8 + l]; f1 = H[u1 * 8 + l];                                  \
    f2 = H[u2 * 8 + l]; f3 = H[u3 * 8 + l];                                  \
    f4 = H[u4 * 8 + l]; f5 = H[u5 * 8 + l];                                  \
    f6 = H[u6 * 8 + l]; f7 = H[u7 * 8 + l];                                  \
    i0 = invn[u0]; i1 = invn[u1]; i2 = invn[u2]; i3 = invn[u3];              \
    i4 = invn[u4]; i5 = invn[u5]; i6 = invn[u6]; i7 = invn[u7];              \
  }

__global__ __launch_bounds__(256) void k_prop(
    const int* __restrict__ rowptr, const int* __restrict__ col,
    const hf* __restrict__ hx, const float* __restrict__ invn,
    const float* __restrict__ beta_p,
    hf* __restrict__ hxo, float* __restrict__ invno) {
  int node = blockIdx.x * 32 + (threadIdx.x >> 3);
  int l = threadIdx.x & 7;                 // lane owns features 2l, 2l+1
  if (node >= NN) return;
  float beta = beta_p ? beta_p[0] : 1.0f;
  const hf2* H = (const hf2*)hx;
  hf2 xi2 = H[node * 8 + l];
  float x0 = (float)xi2.x, x1 = (float)xi2.y;
  float invi = invn[node];
  float n2 = x0 * x0 + x1 * x1;
  n2 += __shfl_xor(n2, 1); n2 += __shfl_xor(n2, 2); n2 += __shfl_xor(n2, 4);
  hf2 xdn2; xdn2.x = (hf)(x0 * invi); xdn2.y = (hf)(x1 * invi);
  float dself = n2 * invi * invi;          // ||xn_i||^2
  float es = __expf(beta * dself);
  float s = es;
  float a0 = es * x0, a1 = es * x1;        // acc (2 features per lane)
  int e = rowptr[node], e2 = rowptr[node + 1];
  hf2 f0, f1, f2, f3, f4, f5, f6, f7;
  float i0, i1, i2, i3, i4, i5, i6, i7;
  if (e + 8 <= e2) PROP_LOAD8(e);          // prologue: load group 0
  for (; e + 16 <= e2; e += 8) {           // steady: consume 8, prefetch 8
    hf2 c0 = f0, c1 = f1, c2 = f2, c3 = f3, c4 = f4, c5 = f5, c6 = f6, c7 = f7;
    float j0 = i0, j1 = i1, j2 = i2, j3 = i3, j4 = i4, j5 = i5, j6 = i6, j7 = i7;
    PROP_LOAD8(e + 8);
    PROP_COMPUTE4(c0, c1, c2, c3, j0, j1, j2, j3);
    PROP_COMPUTE4(c4, c5, c6, c7, j4, j5, j6, j7);
  }
  if (e + 8 <= e2) {                       // drain pipelined group
    PROP_COMPUTE4(f0, f1, f2, f3, i0, i1, i2, i3);
    PROP_COMPUTE4(f4, f5, f6, f7, i4, i5, i6, i7);
    e += 8;
  }
  if (e + 4 <= e2) {                       // 4-wide remainder
    int u0 = col[e], u1 = col[e + 1], u2 = col[e + 2], u3 = col[e + 3];
    hf2 c0 = H[u0 * 8 + l], c1 = H[u1 * 8 + l];
    hf2 c2 = H[u2 * 8 + l], c3 = H[u3 * 8 + l];
    float j0 = invn[u0], j1 = invn[u1], j2 = invn[u2], j3 = invn[u3];
    PROP_COMPUTE4(c0, c1, c2, c3, j0, j1, j2, j3);
    e += 4;
  }
  for (; e < e2; ++e) {                    // tail singles
    int u = col[e];
    hf2 b = H[u * 8 + l];
    float r = dot2f(xdn2, b);
    r += __shfl_xor(r, 1); r += __shfl_xor(r, 2); r += __shfl_xor(r, 4);
    float ee = __expf(beta * r * invn[u]);
    s += ee;
    a0 = fmaf(ee, (float)b.x, a0); a1 = fmaf(ee, (float)b.y, a1);
  }
  float inv_s = 1.0f / s;
  hf2 o; o.x = (hf)(a0 * inv_s); o.y = (hf)(a1 * inv_s);
  float g0 = (float)o.x, g1 = (float)o.y;
  float m2 = g0 * g0 + g1 * g1;
  m2 += __shfl_xor(m2, 1); m2 += __shfl_xor(m2, 2); m2 += __shfl_xor(m2, 4);
  ((hf2*)hxo)[node * 8 + l] = o;
  if (l == 0) invno[node] = rsqrtf(fmaxf(m2, 1e-24f));
}

// ---------------- classifier + log_softmax (fp16 input) ---------------------
__global__ __launch_bounds__(256) void k_cls(
    const hf* __restrict__ x, const float* __restrict__ W2,
    const float* __restrict__ b2, float* __restrict__ out) {
  __shared__ float sW[HID * NCLS];
  __shared__ float sb[NCLS];
  for (int i = threadIdx.x; i < HID * NCLS; i += 256) sW[i] = W2[i];
  if (threadIdx.x < NCLS) sb[threadIdx.x] = b2[threadIdx.x];
  __syncthreads();
  int i = blockIdx.x * 256 + threadIdx.x;
  if (i >= NN) return;
  float xi[HID];
  const hf2* X = (const hf2*)(x + (size_t)i * HID);
#pragma unroll
  for (int r = 0; r < 8; ++r) {
    hf2 v = X[r];
    xi[2 * r] = (float)v.x; xi[2 * r + 1] = (float)v.y;
  }
  float logit[NCLS];
  float mx = -1e30f;
#pragma unroll
  for (int c = 0; c < NCLS; ++c) {
    float acc = sb[c];
#pragma unroll
    for (int kk = 0; kk < HID; ++kk) acc = fmaf(xi[kk], sW[kk * NCLS + c], acc);
    logit[c] = acc;
    mx = fmaxf(mx, acc);
  }
  float ssum = 0.0f;
#pragma unroll
  for (int c = 0; c < NCLS; ++c) ssum += __expf(logit[c] - mx);
  float lse = mx + logf(ssum);
  float* o = out + (size_t)i * NCLS;
#pragma unroll
  for (int c = 0; c < NCLS; ++c) o[c] = logit[c] - lse;
}

extern "C" void kernel_launch(void* const* d_in, const int* in_sizes, int n_in,
                              void* d_out, int out_size, void* d_ws, size_t ws_size,
                              hipStream_t stream) {
  const int*   x_ids = (const int*)d_in[0];
  const int*   ei    = (const int*)d_in[1];   // [2, E]: row0 = src, row1 = dst
  const float* emb   = (const float*)d_in[2];
  const float* W1    = (const float*)d_in[3];
  const float* b1    = (const float*)d_in[4];
  const float* beta2 = (const float*)d_in[5];
  const float* W2    = (const float*)d_in[6];
  const float* b2    = (const float*)d_in[7];
  float* out = (float*)d_out;

  // workspace: [strm NE u32 | col NE | rowptr | gcount | gbase | gcur]
  // strm is dead after kD; fp16 feature pipeline aliases it (7.2 MB < 12.8 MB).
  unsigned* strm = (unsigned*)d_ws;
  int* col    = (int*)d_ws + NE;
  int* rowptr = col + NE;
  int* gcount = rowptr + (NN + 1);
  int* gbase  = gcount + NBKT;
  int* gcur   = gbase + NBKT;
  hf*    hx0   = (hf*)d_ws;                      // [NN*HID] 3.2 MB
  hf*    hx1   = hx0 + (size_t)NN * HID;         // [NN*HID] 3.2 MB
  float* invn0 = (float*)(hx1 + (size_t)NN * HID);   // [NN] 0.4 MB
  float* invn1 = invn0 + NN;                     // [NN] 0.4 MB

  const int* esrc = ei;
  const int* edst = ei + NE;

  const int gN = (NN + 255) / 256;
  const int gM = (NN + 15) / 16;
  const int gP = (NN + 31) / 32;

  // CSR build (self-loops handled analytically in k_prop)
  k_zero<<<2, 256, 0, stream>>>(gcount, NBKT);
  kA<<<NBLKC, TB, 0, stream>>>(edst, gcount);
  kB<<<1, 512, 0, stream>>>(gcount, gbase, gcur, rowptr);
  kC<<<NBLKC, TB, 0, stream>>>(esrc, edst, gcur, strm);
  kD<<<NBKT, TB, 0, stream>>>(gcount, gbase, strm, rowptr, col);

  // features (fp16 + invn), aliasing strm (dead after kD)
  k_embed_mlp<<<gM, 256, 0, stream>>>(x_ids, emb, W1, b1, hx0, invn0);

  // prop1 (beta = 1.0), prop2 (beta = beta2)
  k_prop<<<gP, 256, 0, stream>>>(rowptr, col, hx0, invn0, nullptr, hx1, invn1);
  k_prop<<<gP, 256, 0, stream>>>(rowptr, col, hx1, invn1, beta2, hx0, invn0);

  k_cls<<<gN, 256, 0, stream>>>(hx0, W2, b2, out);
}